// Round 1
// baseline (269.139 us; speedup 1.0000x reference)
//
#include <hip/hip_runtime.h>
#include <math.h>

// Problem constants (from reference)
#define GRID_N 544          // NUM_GRID = ceil(128*4.2/16)*16
#define BATCH  8
#define NPTS   2048
#define MPTS   2048
#define XMIN_F (-2.1f)
#define STEP_F (4.2f / 543.0f)   // linspace step, endpoint inclusive

// Workspace layout (floats):
// prm[0..127]: [0..1]=a_enc (0.5*exp(-2*sigma)), [8..15]=a_mean, [16..23]=a_sig,
//              [24..87]=S (8x8 = sig_W sig_W^T), [88..95]=u (sig_W@sig_b),
//              [96]=s0 (sig_b.sig_b), [97]=exp(noise_scale)
#define PRM_OFF 0
#define H_OFF   128                        // h: B*G*8 = 34816 floats
#define FS_OFF  (H_OFF + BATCH*GRID_N*8)   // feat_sig: B*M*8 = 131072
#define P_OFF   (FS_OFF + BATCH*MPTS*8)    // P = feat_sig@S + u: B*M*8
#define CM_OFF  (P_OFF + BATCH*MPTS*8)     // c_m: B*M
// total = 128 + 34816 + 131072*2 + 16384 = 313472 floats ~ 1.25 MB

// ---------------------------------------------------------------- K0: params
__global__ __launch_bounds__(256) void k_params(
    const float* __restrict__ enc_sigma, const float* __restrict__ mean_sigma,
    const float* __restrict__ sig_sigma, const float* __restrict__ sig_W,
    const float* __restrict__ sig_b, const float* __restrict__ noise_scale,
    float* __restrict__ prm) {
  int t = threadIdx.x;
  __shared__ float part[256];
  // S[i][j] = sum_k sig_W[i,k]*sig_W[j,k]; 64 pairs x 4 k-slices of 256
  int pair = t >> 2, q = t & 3;
  int i = pair >> 3, j = pair & 7;
  float s = 0.f;
  int k0 = q * 256;
  for (int k = k0; k < k0 + 256; ++k) s += sig_W[i*1024+k] * sig_W[j*1024+k];
  part[t] = s;
  __syncthreads();
  if (q == 0) prm[24 + pair] = part[t] + part[t+1] + part[t+2] + part[t+3];
  if (t < 8) {
    float u = 0.f;
    for (int k = 0; k < 1024; ++k) u += sig_W[t*1024+k] * sig_b[k];
    prm[88 + t] = u;
  } else if (t == 8) {
    float v = 0.f;
    for (int k = 0; k < 1024; ++k) v += sig_b[k] * sig_b[k];
    prm[96] = v;
  } else if (t == 9) {
    prm[97] = __expf(noise_scale[0]);
  } else if (t == 10 || t == 11) {
    prm[t - 10] = 0.5f * __expf(-2.f * enc_sigma[t - 10]);
  } else if (t >= 16 && t < 24) {
    prm[8 + (t - 16)] = 0.5f * __expf(-2.f * mean_sigma[t - 16]);
  } else if (t >= 24 && t < 32) {
    prm[16 + (t - 24)] = 0.5f * __expf(-2.f * sig_sigma[t - 24]);
  }
}

// ------------------------------------------------------------- K1: encoder
// One block per (b,g): F0 = sum_n w0, F1 = sum_n y*w1, then tiny MLP -> h[b,g,0..7]
__global__ __launch_bounds__(256) void k_encode(
    const float* __restrict__ x, const float* __restrict__ y,
    const float* __restrict__ enc_W, const float* __restrict__ enc_b,
    const float* __restrict__ rho_W, const float* __restrict__ rho_b,
    const float* __restrict__ prm, float* __restrict__ h_out) {
  int b = blockIdx.y, g = blockIdx.x, t = threadIdx.x;
  float gv = XMIN_F + (float)g * STEP_F;
  float a0 = prm[0], a1 = prm[1];
  const float* xb = x + b * NPTS;
  const float* yb = y + b * NPTS;
  float s0 = 0.f, s1 = 0.f;
  for (int n = t; n < NPTS; n += 256) {
    float dx = xb[n] - gv;
    float d = dx * dx;
    s0 += __expf(-d * a0);
    s1 += yb[n] * __expf(-d * a1);
  }
  __shared__ float r0[256], r1[256];
  r0[t] = s0; r1[t] = s1;
  __syncthreads();
  for (int off = 128; off > 0; off >>= 1) {
    if (t < off) { r0[t] += r0[t + off]; r1[t] += r1[t + off]; }
    __syncthreads();
  }
  if (t == 0) {
    float den = r0[0], conv = r1[0];
    float F0 = den, F1 = conv / (den + 1e-8f);
    float hh[8];
    #pragma unroll
    for (int jj = 0; jj < 8; ++jj) {
      float z = F0 * enc_W[jj] + F1 * enc_W[8 + jj] + enc_b[jj];
      hh[jj] = 1.f / (1.f + __expf(-z));
    }
    #pragma unroll
    for (int jj = 0; jj < 8; ++jj) {
      float v = rho_b[jj];
      #pragma unroll
      for (int ii = 0; ii < 8; ++ii) v += hh[ii] * rho_W[ii*8 + jj];
      h_out[((size_t)b * GRID_N + g) * 8 + jj] = v;
    }
  }
}

// ------------------------------------------------------------- K2: decoder feats
// block = 256 = 64 m-lanes x 4 g-slices (136 g each). Computes mean output,
// feat_sig, P = feat_sig@S + u, c_m = feat_sig.u + s0.
__global__ __launch_bounds__(256) void k_feat(
    const float* __restrict__ x_out, const float* __restrict__ mean_W,
    const float* __restrict__ mean_b, const float* __restrict__ prm,
    const float* __restrict__ h, float* __restrict__ mean_out,
    float* __restrict__ fS, float* __restrict__ Pv, float* __restrict__ cm) {
  int b = blockIdx.y, t = threadIdx.x;
  int ml = t & 63, slice = t >> 6;
  int m = blockIdx.x * 64 + ml;
  float xo = x_out[(size_t)b * MPTS + m];
  float am[8], asg[8];
  #pragma unroll
  for (int c = 0; c < 8; ++c) { am[c] = prm[8 + c]; asg[c] = prm[16 + c]; }
  float accm[8] = {0,0,0,0,0,0,0,0};
  float accs[8] = {0,0,0,0,0,0,0,0};
  const float* hb = h + (size_t)b * GRID_N * 8;
  int gbase = slice * 136;
  for (int gg = 0; gg < 136; ++gg) {
    int g = gbase + gg;
    float gv = XMIN_F + (float)g * STEP_F;
    float dx = gv - xo;
    float d = dx * dx;
    #pragma unroll
    for (int c = 0; c < 8; ++c) {
      float hv = hb[g*8 + c];
      accm[c] += hv * __expf(-d * am[c]);
      accs[c] += hv * __expf(-d * asg[c]);
    }
  }
  __shared__ float red[256 * 16];
  #pragma unroll
  for (int c = 0; c < 8; ++c) { red[t*16 + c] = accm[c]; red[t*16 + 8 + c] = accs[c]; }
  __syncthreads();
  if (t < 64) {
    int mm = blockIdx.x * 64 + t;
    float fm[8], fs[8];
    #pragma unroll
    for (int c = 0; c < 8; ++c) {
      fm[c] = red[t*16+c] + red[(t+64)*16+c] + red[(t+128)*16+c] + red[(t+192)*16+c];
      fs[c] = red[t*16+8+c] + red[(t+64)*16+8+c] + red[(t+128)*16+8+c] + red[(t+192)*16+8+c];
    }
    float mv = mean_b[0];
    #pragma unroll
    for (int c = 0; c < 8; ++c) mv += fm[c] * mean_W[c];
    mean_out[(size_t)b * MPTS + mm] = mv;
    float cmv = prm[96];
    #pragma unroll
    for (int c = 0; c < 8; ++c) cmv += fs[c] * prm[88 + c];
    cm[(size_t)b * MPTS + mm] = cmv;
    size_t base = ((size_t)b * MPTS + mm) * 8;
    #pragma unroll
    for (int c2 = 0; c2 < 8; ++c2) {
      float p = prm[88 + c2];
      #pragma unroll
      for (int c = 0; c < 8; ++c) p += fs[c] * prm[24 + c*8 + c2];
      Pv[base + c2] = p;
    }
    #pragma unroll
    for (int c = 0; c < 8; ++c) fS[base + c] = fs[c];
  }
}

// ------------------------------------------------------------- K3: covariance
// cov[b,m,n] = P[b,m,:].f[b,n,:] + c_m (+ noise on diag). Write-BW bound.
// block = 256 threads x 8 n-cols each; 16 m-rows per block.
__global__ __launch_bounds__(256) void k_cov(
    const float* __restrict__ fS, const float* __restrict__ Pv,
    const float* __restrict__ cm, const float* __restrict__ prm,
    float* __restrict__ cov) {
  int b = blockIdx.y, t = threadIdx.x;
  int mt = blockIdx.x * 16;
  int n0 = t * 8;
  // load f for my 8 columns (8 rows x 8 channels = 16 float4)
  float fn[8][8];
  const float4* fv = (const float4*)(fS + ((size_t)b * MPTS + n0) * 8);
  #pragma unroll
  for (int j = 0; j < 8; ++j) {
    float4 lo = fv[j*2], hi = fv[j*2+1];
    fn[j][0]=lo.x; fn[j][1]=lo.y; fn[j][2]=lo.z; fn[j][3]=lo.w;
    fn[j][4]=hi.x; fn[j][5]=hi.y; fn[j][6]=hi.z; fn[j][7]=hi.w;
  }
  __shared__ float Ps[16*8];
  __shared__ float Cs[16];
  if (t < 128) Ps[t] = Pv[((size_t)b * MPTS + mt) * 8 + t];
  if (t < 16)  Cs[t] = cm[(size_t)b * MPTS + mt + t];
  float noise = prm[97];
  __syncthreads();
  #pragma unroll 1
  for (int mi = 0; mi < 16; ++mi) {
    float p[8];
    #pragma unroll
    for (int c = 0; c < 8; ++c) p[c] = Ps[mi*8 + c];
    float cc = Cs[mi];
    float o[8];
    #pragma unroll
    for (int j = 0; j < 8; ++j) {
      float acc = cc;
      #pragma unroll
      for (int c = 0; c < 8; ++c) acc += p[c] * fn[j][c];
      o[j] = acc;
    }
    int mg = mt + mi;
    if (mg >= n0 && mg < n0 + 8) o[mg - n0] += noise;
    float4* outp = (float4*)(cov + ((size_t)b * MPTS + mg) * MPTS + n0);
    outp[0] = make_float4(o[0], o[1], o[2], o[3]);
    outp[1] = make_float4(o[4], o[5], o[6], o[7]);
  }
}

extern "C" void kernel_launch(void* const* d_in, const int* in_sizes, int n_in,
                              void* d_out, int out_size, void* d_ws, size_t ws_size,
                              hipStream_t stream) {
  const float* x          = (const float*)d_in[0];
  const float* y          = (const float*)d_in[1];
  const float* x_out      = (const float*)d_in[2];
  const float* enc_sigma  = (const float*)d_in[3];
  const float* enc_W      = (const float*)d_in[4];
  const float* enc_b      = (const float*)d_in[5];
  const float* rho_W      = (const float*)d_in[6];
  const float* rho_b      = (const float*)d_in[7];
  const float* mean_sigma = (const float*)d_in[8];
  const float* mean_W     = (const float*)d_in[9];
  const float* mean_b     = (const float*)d_in[10];
  const float* sig_sigma  = (const float*)d_in[11];
  const float* sig_W      = (const float*)d_in[12];
  const float* sig_b      = (const float*)d_in[13];
  const float* noise_sc   = (const float*)d_in[14];

  float* wsf = (float*)d_ws;
  float* prm = wsf + PRM_OFF;
  float* hbuf = wsf + H_OFF;
  float* fSb = wsf + FS_OFF;
  float* Pb  = wsf + P_OFF;
  float* cmb = wsf + CM_OFF;

  float* mean_out = (float*)d_out;                  // B*M floats
  float* cov_out  = mean_out + (size_t)BATCH * MPTS; // B*M*M floats

  k_params<<<1, 256, 0, stream>>>(enc_sigma, mean_sigma, sig_sigma,
                                  sig_W, sig_b, noise_sc, prm);
  k_encode<<<dim3(GRID_N, BATCH), 256, 0, stream>>>(x, y, enc_W, enc_b,
                                                    rho_W, rho_b, prm, hbuf);
  k_feat<<<dim3(MPTS/64, BATCH), 256, 0, stream>>>(x_out, mean_W, mean_b, prm,
                                                   hbuf, mean_out, fSb, Pb, cmb);
  k_cov<<<dim3(MPTS/16, BATCH), 256, 0, stream>>>(fSb, Pb, cmb, prm, cov_out);
}

// Round 2
// 221.866 us; speedup vs baseline: 1.2131x; 1.2131x over previous
//
#include <hip/hip_runtime.h>
#include <math.h>

// Problem constants (from reference)
#define GRID_N 544          // NUM_GRID = ceil(128*4.2/16)*16
#define BATCH  8
#define NPTS   2048
#define MPTS   2048
#define XMIN_F (-2.1f)
#define STEP_F (4.2f / 543.0f)   // linspace step, endpoint inclusive

// Workspace layout (floats):
// prm: [0..1]=a_enc (0.5*exp(-2*sigma)), [8..15]=a_mean, [16..23]=a_sig,
//      [24..87]=S (8x8 = sig_W sig_W^T), [88..95]=u (sig_W@sig_b),
//      [96]=s0 (sig_b.sig_b), [97]=exp(noise_scale),
//      [98]=flag_enc_uniform, [99]=flag_mean_uniform, [100]=flag_sig_uniform,
//      [101]=flag_mean_eq_sig (all 16 scales identical)
#define PRM_OFF 0
#define H_OFF   128                        // h: B*G*8 = 34816 floats
#define FS_OFF  (H_OFF + BATCH*GRID_N*8)   // feat_sig: B*M*8 = 131072
#define P_OFF   (FS_OFF + BATCH*MPTS*8)    // P = feat_sig@S + u: B*M*8
#define CM_OFF  (P_OFF + BATCH*MPTS*8)     // c_m: B*M

// ---------------------------------------------------------------- K0: params
__global__ __launch_bounds__(256) void k_params(
    const float* __restrict__ enc_sigma, const float* __restrict__ mean_sigma,
    const float* __restrict__ sig_sigma, const float* __restrict__ sig_W,
    const float* __restrict__ sig_b, const float* __restrict__ noise_scale,
    float* __restrict__ prm) {
  int t = threadIdx.x;
  __shared__ float part[256];
  // S[i][j] = sum_k sig_W[i,k]*sig_W[j,k]; 64 pairs x 4 k-slices of 256
  {
    int pair = t >> 2, q = t & 3;
    int i = pair >> 3, j = pair & 7;
    float s = 0.f;
    int k0 = q * 256;
    for (int k = k0; k < k0 + 256; ++k) s += sig_W[i*1024+k] * sig_W[j*1024+k];
    part[t] = s;
    __syncthreads();
    if (q == 0) prm[24 + pair] = part[t] + part[t+1] + part[t+2] + part[t+3];
    __syncthreads();
  }
  // u[ch] = sig_W[ch,:].sig_b  (32 threads per channel)
  {
    int ch = t >> 5, lane = t & 31;
    float s = 0.f;
    for (int k = lane; k < 1024; k += 32) s += sig_W[ch*1024+k] * sig_b[k];
    part[t] = s;
    __syncthreads();
    if (lane == 0) {
      float acc = 0.f;
      for (int k = 0; k < 32; ++k) acc += part[(ch<<5)+k];
      prm[88 + ch] = acc;
    }
    __syncthreads();
  }
  // s0 = sig_b.sig_b (32 threads)
  if (t < 32) {
    float v = 0.f;
    for (int k = t; k < 1024; k += 32) v += sig_b[k] * sig_b[k];
    part[t] = v;
  }
  __syncthreads();
  if (t == 0) {
    float v = 0.f;
    for (int k = 0; k < 32; ++k) v += part[k];
    prm[96] = v;
    prm[97] = __expf(noise_scale[0]);
  } else if (t == 1) {
    // scale coefficients + uniformity flags
    prm[0] = 0.5f * __expf(-2.f * enc_sigma[0]);
    prm[1] = 0.5f * __expf(-2.f * enc_sigma[1]);
    prm[98] = (enc_sigma[0] == enc_sigma[1]) ? 1.f : 0.f;
    bool mu = true, su = true;
    for (int c = 0; c < 8; ++c) {
      prm[8 + c]  = 0.5f * __expf(-2.f * mean_sigma[c]);
      prm[16 + c] = 0.5f * __expf(-2.f * sig_sigma[c]);
      if (mean_sigma[c] != mean_sigma[0]) mu = false;
      if (sig_sigma[c]  != sig_sigma[0])  su = false;
    }
    prm[99]  = mu ? 1.f : 0.f;
    prm[100] = su ? 1.f : 0.f;
    prm[101] = (mu && su && mean_sigma[0] == sig_sigma[0]) ? 1.f : 0.f;
  }
}

// ------------------------------------------------------------- K1: encoder
// One block per (b,g): F0 = sum_n w0, F1 = sum_n y*w1, then tiny MLP -> h[b,g,0..7]
__global__ __launch_bounds__(256) void k_encode(
    const float* __restrict__ x, const float* __restrict__ y,
    const float* __restrict__ enc_W, const float* __restrict__ enc_b,
    const float* __restrict__ rho_W, const float* __restrict__ rho_b,
    const float* __restrict__ prm, float* __restrict__ h_out) {
  int b = blockIdx.y, g = blockIdx.x, t = threadIdx.x;
  float gv = XMIN_F + (float)g * STEP_F;
  float a0 = prm[0], a1 = prm[1];
  bool uni = prm[98] != 0.f;
  const float4* x4 = (const float4*)(x + (size_t)b * NPTS);
  const float4* y4 = (const float4*)(y + (size_t)b * NPTS);
  float s0 = 0.f, s1 = 0.f;
  #pragma unroll
  for (int i = 0; i < 2; ++i) {
    int n = i * 256 + t;
    float4 xv = x4[n], yv = y4[n];
    float dx, d, w;
    dx = xv.x - gv; d = dx*dx; w = __expf(-d*a0); s0 += w;
    s1 += yv.x * (uni ? w : __expf(-d*a1));
    dx = xv.y - gv; d = dx*dx; w = __expf(-d*a0); s0 += w;
    s1 += yv.y * (uni ? w : __expf(-d*a1));
    dx = xv.z - gv; d = dx*dx; w = __expf(-d*a0); s0 += w;
    s1 += yv.z * (uni ? w : __expf(-d*a1));
    dx = xv.w - gv; d = dx*dx; w = __expf(-d*a0); s0 += w;
    s1 += yv.w * (uni ? w : __expf(-d*a1));
  }
  // wave reduce
  #pragma unroll
  for (int off = 32; off > 0; off >>= 1) {
    s0 += __shfl_down(s0, off);
    s1 += __shfl_down(s1, off);
  }
  __shared__ float w0s[4], w1s[4];
  int wid = t >> 6;
  if ((t & 63) == 0) { w0s[wid] = s0; w1s[wid] = s1; }
  __syncthreads();
  if (t == 0) {
    float den = w0s[0] + w0s[1] + w0s[2] + w0s[3];
    float conv = w1s[0] + w1s[1] + w1s[2] + w1s[3];
    float F0 = den, F1 = conv / (den + 1e-8f);
    float hh[8];
    #pragma unroll
    for (int jj = 0; jj < 8; ++jj) {
      float z = F0 * enc_W[jj] + F1 * enc_W[8 + jj] + enc_b[jj];
      hh[jj] = 1.f / (1.f + __expf(-z));
    }
    #pragma unroll
    for (int jj = 0; jj < 8; ++jj) {
      float v = rho_b[jj];
      #pragma unroll
      for (int ii = 0; ii < 8; ++ii) v += hh[ii] * rho_W[ii*8 + jj];
      h_out[((size_t)b * GRID_N + g) * 8 + jj] = v;
    }
  }
}

// ------------------------------------------------------------- K2: decoder feats
// block = 256 = 64 m-lanes x 4 g-slices (136 g each). Computes mean output,
// feat_sig, P = feat_sig@S + u, c_m = feat_sig.u + s0.
// Fast path (all 16 RBF scales identical): 1 exp + 8 FMA per g, fm == fs.
__global__ __launch_bounds__(256) void k_feat(
    const float* __restrict__ x_out, const float* __restrict__ mean_W,
    const float* __restrict__ mean_b, const float* __restrict__ prm,
    const float* __restrict__ h, float* __restrict__ mean_out,
    float* __restrict__ fS, float* __restrict__ Pv, float* __restrict__ cm) {
  int b = blockIdx.y, t = threadIdx.x;
  int ml = t & 63, slice = t >> 6;
  int m = blockIdx.x * 64 + ml;
  float xo = x_out[(size_t)b * MPTS + m];
  bool fused = prm[101] != 0.f;
  float accm[8] = {0,0,0,0,0,0,0,0};
  float accs[8] = {0,0,0,0,0,0,0,0};
  const float* hb = h + (size_t)b * GRID_N * 8;
  const float4* h4 = (const float4*)hb;
  int gbase = slice * 136;
  if (fused) {
    float a = prm[8];  // == all of a_mean, a_sig
    for (int gg = 0; gg < 136; ++gg) {
      int g = gbase + gg;
      float gv = XMIN_F + (float)g * STEP_F;
      float dx = gv - xo;
      float w = __expf(-(dx*dx) * a);
      float4 h0 = h4[g*2], h1 = h4[g*2+1];
      accm[0] += h0.x * w; accm[1] += h0.y * w;
      accm[2] += h0.z * w; accm[3] += h0.w * w;
      accm[4] += h1.x * w; accm[5] += h1.y * w;
      accm[6] += h1.z * w; accm[7] += h1.w * w;
    }
    #pragma unroll
    for (int c = 0; c < 8; ++c) accs[c] = accm[c];
  } else {
    float am[8], asg[8];
    #pragma unroll
    for (int c = 0; c < 8; ++c) { am[c] = prm[8 + c]; asg[c] = prm[16 + c]; }
    for (int gg = 0; gg < 136; ++gg) {
      int g = gbase + gg;
      float gv = XMIN_F + (float)g * STEP_F;
      float dx = gv - xo;
      float d = dx * dx;
      #pragma unroll
      for (int c = 0; c < 8; ++c) {
        float hv = hb[g*8 + c];
        accm[c] += hv * __expf(-d * am[c]);
        accs[c] += hv * __expf(-d * asg[c]);
      }
    }
  }
  __shared__ float red[256 * 17];   // stride 17: bank-conflict-free
  #pragma unroll
  for (int c = 0; c < 8; ++c) { red[t*17 + c] = accm[c]; red[t*17 + 8 + c] = accs[c]; }
  __syncthreads();
  if (t < 64) {
    int mm = blockIdx.x * 64 + t;
    float fm[8], fs[8];
    #pragma unroll
    for (int c = 0; c < 8; ++c) {
      fm[c] = red[t*17+c] + red[(t+64)*17+c] + red[(t+128)*17+c] + red[(t+192)*17+c];
      fs[c] = red[t*17+8+c] + red[(t+64)*17+8+c] + red[(t+128)*17+8+c] + red[(t+192)*17+8+c];
    }
    float mv = mean_b[0];
    #pragma unroll
    for (int c = 0; c < 8; ++c) mv += fm[c] * mean_W[c];
    mean_out[(size_t)b * MPTS + mm] = mv;
    float cmv = prm[96];
    #pragma unroll
    for (int c = 0; c < 8; ++c) cmv += fs[c] * prm[88 + c];
    cm[(size_t)b * MPTS + mm] = cmv;
    size_t base = ((size_t)b * MPTS + mm) * 8;
    #pragma unroll
    for (int c2 = 0; c2 < 8; ++c2) {
      float p = prm[88 + c2];
      #pragma unroll
      for (int c = 0; c < 8; ++c) p += fs[c] * prm[24 + c*8 + c2];
      Pv[base + c2] = p;
    }
    #pragma unroll
    for (int c = 0; c < 8; ++c) fS[base + c] = fs[c];
  }
}

// ------------------------------------------------------------- K3: covariance
// cov[b,m,n] = P[b,m,:].f[b,n,:] + c_m (+ noise on diag). Write-BW bound.
// block = 256 threads x 8 n-cols each; 16 m-rows per block.
__global__ __launch_bounds__(256) void k_cov(
    const float* __restrict__ fS, const float* __restrict__ Pv,
    const float* __restrict__ cm, const float* __restrict__ prm,
    float* __restrict__ cov) {
  int b = blockIdx.y, t = threadIdx.x;
  int mt = blockIdx.x * 16;
  int n0 = t * 8;
  // load f for my 8 columns (8 rows x 8 channels = 16 float4)
  float fn[8][8];
  const float4* fv = (const float4*)(fS + ((size_t)b * MPTS + n0) * 8);
  #pragma unroll
  for (int j = 0; j < 8; ++j) {
    float4 lo = fv[j*2], hi = fv[j*2+1];
    fn[j][0]=lo.x; fn[j][1]=lo.y; fn[j][2]=lo.z; fn[j][3]=lo.w;
    fn[j][4]=hi.x; fn[j][5]=hi.y; fn[j][6]=hi.z; fn[j][7]=hi.w;
  }
  __shared__ float Ps[16*8];
  __shared__ float Cs[16];
  if (t < 128) Ps[t] = Pv[((size_t)b * MPTS + mt) * 8 + t];
  if (t < 16)  Cs[t] = cm[(size_t)b * MPTS + mt + t];
  float noise = prm[97];
  __syncthreads();
  #pragma unroll 1
  for (int mi = 0; mi < 16; ++mi) {
    float p[8];
    #pragma unroll
    for (int c = 0; c < 8; ++c) p[c] = Ps[mi*8 + c];
    float cc = Cs[mi];
    float o[8];
    #pragma unroll
    for (int j = 0; j < 8; ++j) {
      float acc = cc;
      #pragma unroll
      for (int c = 0; c < 8; ++c) acc += p[c] * fn[j][c];
      o[j] = acc;
    }
    int mg = mt + mi;
    if (mg >= n0 && mg < n0 + 8) o[mg - n0] += noise;
    float4* outp = (float4*)(cov + ((size_t)b * MPTS + mg) * MPTS + n0);
    outp[0] = make_float4(o[0], o[1], o[2], o[3]);
    outp[1] = make_float4(o[4], o[5], o[6], o[7]);
  }
}

extern "C" void kernel_launch(void* const* d_in, const int* in_sizes, int n_in,
                              void* d_out, int out_size, void* d_ws, size_t ws_size,
                              hipStream_t stream) {
  const float* x          = (const float*)d_in[0];
  const float* y          = (const float*)d_in[1];
  const float* x_out      = (const float*)d_in[2];
  const float* enc_sigma  = (const float*)d_in[3];
  const float* enc_W      = (const float*)d_in[4];
  const float* enc_b      = (const float*)d_in[5];
  const float* rho_W      = (const float*)d_in[6];
  const float* rho_b      = (const float*)d_in[7];
  const float* mean_sigma = (const float*)d_in[8];
  const float* mean_W     = (const float*)d_in[9];
  const float* mean_b     = (const float*)d_in[10];
  const float* sig_sigma  = (const float*)d_in[11];
  const float* sig_W      = (const float*)d_in[12];
  const float* sig_b      = (const float*)d_in[13];
  const float* noise_sc   = (const float*)d_in[14];

  float* wsf = (float*)d_ws;
  float* prm = wsf + PRM_OFF;
  float* hbuf = wsf + H_OFF;
  float* fSb = wsf + FS_OFF;
  float* Pb  = wsf + P_OFF;
  float* cmb = wsf + CM_OFF;

  float* mean_out = (float*)d_out;                   // B*M floats
  float* cov_out  = mean_out + (size_t)BATCH * MPTS; // B*M*M floats

  k_params<<<1, 256, 0, stream>>>(enc_sigma, mean_sigma, sig_sigma,
                                  sig_W, sig_b, noise_sc, prm);
  k_encode<<<dim3(GRID_N, BATCH), 256, 0, stream>>>(x, y, enc_W, enc_b,
                                                    rho_W, rho_b, prm, hbuf);
  k_feat<<<dim3(MPTS/64, BATCH), 256, 0, stream>>>(x_out, mean_W, mean_b, prm,
                                                   hbuf, mean_out, fSb, Pb, cmb);
  k_cov<<<dim3(MPTS/16, BATCH), 256, 0, stream>>>(fSb, Pb, cmb, prm, cov_out);
}